// Round 1
// baseline (98.778 us; speedup 1.0000x reference)
//
#include <hip/hip_runtime.h>
#include <math.h>

// Problem constants (fixed by setup_inputs)
#define NPRIM   512
#define TOPK    8
#define PSTRIDE 28               // floats per primitive record (7 x float4)
#define IMG     200
#define NPIX    (IMG * IMG)
#define NSEG    8                // depth segments = waves per block
#define SEGSZ   (NPRIM / NSEG)   // 64 prims per wave
#define TILE    64               // 8x8 pixel tile, one pixel per lane
#define TILES_X (IMG / 8)        // 25
#define NTILES  (TILES_X * TILES_X)  // 625
#define GRID    209              // ceil(625/3): <=3 tiles/block, <=1 block/CU

// LDS record layout (float4 granularity):
// f4[0]: px py conA conB | f4[1]: conC a2x a2y op | f4[2]: r g b pad
// f4[3..4]: coeff[8]     | f4[5..6]: omega[8]

__global__ __launch_bounds__(NPRIM) void fused_kernel(
    const float* __restrict__ colors,
    const float* __restrict__ opacities,
    const float* __restrict__ positions,
    const float* __restrict__ scales,
    const float* __restrict__ rotations,
    const float* __restrict__ wcoef,
    const int*   __restrict__ widx,
    const float* __restrict__ view,
    const float* __restrict__ VP,
    const float* __restrict__ bg,
    float* __restrict__ out)
{
    __shared__ float  lds[NPRIM * PSTRIDE];   // 57344 B, depth-sorted records
    __shared__ float4 sbb[NPRIM];             //  8192 B, depth-sorted (px,py,rx,ry)
    __shared__ float4 part[NSEG * TILE];      //  8192 B
    __shared__ float  sd[NPRIM];              //  2048 B   (total 75776 B -> 2 blk/CU ok)

    const int n = threadIdx.x;

    // ------------------------------------------------------------------
    // Phase 1: per-primitive projection + depth-rank sort, straight to LDS
    // ------------------------------------------------------------------
    {
        const float tanx = 0.57735026918962576451f; // tan(30 deg)
        const float fx = IMG / (2.0f * tanx);
        const float fy = IMG / (2.0f * tanx);

        float qr = rotations[n*4+0], qx = rotations[n*4+1];
        float qy = rotations[n*4+2], qz = rotations[n*4+3];
        float qn = sqrtf(qr*qr + qx*qx + qy*qy + qz*qz) + 1e-8f;
        qr /= qn; qx /= qn; qy /= qn; qz /= qn;
        float R00 = 1.f - 2.f*(qy*qy + qz*qz), R01 = 2.f*(qx*qy - qr*qz), R02 = 2.f*(qx*qz + qr*qy);
        float R10 = 2.f*(qx*qy + qr*qz), R11 = 1.f - 2.f*(qx*qx + qz*qz), R12 = 2.f*(qy*qz - qr*qx);
        float R20 = 2.f*(qx*qz - qr*qy), R21 = 2.f*(qy*qz + qr*qx), R22 = 1.f - 2.f*(qx*qx + qy*qy);

        float s0 = expf(scales[n*3+0]); s0 *= s0;
        float s1 = expf(scales[n*3+1]); s1 *= s1;
        float s2 = expf(scales[n*3+2]); s2 *= s2;

        float S00 = R00*R00*s0 + R01*R01*s1 + R02*R02*s2;
        float S01 = R00*R10*s0 + R01*R11*s1 + R02*R12*s2;
        float S02 = R00*R20*s0 + R01*R21*s1 + R02*R22*s2;
        float S11 = R10*R10*s0 + R11*R11*s1 + R12*R12*s2;
        float S12 = R10*R20*s0 + R11*R21*s1 + R12*R22*s2;
        float S22 = R20*R20*s0 + R21*R21*s1 + R22*R22*s2;

        float px_ = positions[n*3+0], py_ = positions[n*3+1], pz_ = positions[n*3+2];
        float t0 = view[0]*px_ + view[1]*py_ + view[2]*pz_  + view[3];
        float t1 = view[4]*px_ + view[5]*py_ + view[6]*pz_  + view[7];
        float t2 = view[8]*px_ + view[9]*py_ + view[10]*pz_ + view[11];
        float c0 = VP[0]*px_  + VP[1]*py_  + VP[2]*pz_  + VP[3];
        float c1 = VP[4]*px_  + VP[5]*py_  + VP[6]*pz_  + VP[7];
        float w  = VP[12]*px_ + VP[13]*py_ + VP[14]*pz_ + VP[15];

        float denom = (fabsf(w) > 1e-6f) ? w : 1e-6f;
        float pxs = (c0/denom * 0.5f + 0.5f) * (float)IMG;
        float pys = (c1/denom * 0.5f + 0.5f) * (float)IMG;

        float depth = t2;
        float tz = fmaxf(depth, 0.1f);
        float invz = 1.f / tz;
        float J00 = fx*invz, J02 = -fx*t0*invz*invz;
        float J11 = fy*invz, J12 = -fy*t1*invz*invz;

        float M00 = J00*view[0] + J02*view[8];
        float M01 = J00*view[1] + J02*view[9];
        float M02 = J00*view[2] + J02*view[10];
        float M10 = J11*view[4] + J12*view[8];
        float M11 = J11*view[5] + J12*view[9];
        float M12 = J11*view[6] + J12*view[10];

        float T00 = M00*S00 + M01*S01 + M02*S02;
        float T01 = M00*S01 + M01*S11 + M02*S12;
        float T02 = M00*S02 + M01*S12 + M02*S22;
        float T10 = M10*S00 + M11*S01 + M12*S02;
        float T11 = M10*S01 + M11*S11 + M12*S12;
        float T12 = M10*S02 + M11*S12 + M12*S22;
        float cA = T00*M00 + T01*M01 + T02*M02 + 0.3f;
        float cB = T00*M10 + T01*M11 + T02*M12;
        float cC = T10*M10 + T11*M11 + T12*M12 + 0.3f;
        float det  = fmaxf(cA*cC - cB*cB, 1e-12f);
        float idet = 1.f / det;
        float conA = cC*idet, conB = -cB*idet, conC = cA*idet;

        float a2x = M00*R00 + M01*R10 + M02*R20;
        float a2y = M10*R00 + M11*R10 + M12*R20;
        float an = sqrtf(a2x*a2x + a2y*a2y) + 1e-8f;
        a2x = (a2x/an) * (1.0f/(float)IMG);
        a2y = (a2y/an) * (1.0f/(float)IMG);

        bool valid = (depth > 0.1f) && (w > 1e-4f);
        float op = valid ? opacities[n] : 0.0f;

        // bbox of the {pw >= -15} ellipse: half-extents sqrt(2*15*cov_dilated_diag)
        float rx = valid ? sqrtf(fmaxf(30.f * cA, 0.f)) : -1e30f;
        float ry = valid ? sqrtf(fmaxf(30.f * cC, 0.f)) : -1e30f;

        // rank = #{m : (d_m, m) < (d_n, n)}  (matches stable argsort)
        sd[n] = depth;
        __syncthreads();
        int rank = 0;
#pragma unroll 8
        for (int m = 0; m < NPRIM; ++m) {
            float dm = sd[m];
            rank += (dm < depth) || (dm == depth && m < n);
        }

        float* e = lds + rank * PSTRIDE;
        e[0]=pxs; e[1]=pys; e[2]=conA; e[3]=conB; e[4]=conC;
        e[5]=a2x; e[6]=a2y; e[7]=op;
        e[8]=colors[n*3+0]; e[9]=colors[n*3+1]; e[10]=colors[n*3+2]; e[11]=0.f;
#pragma unroll
        for (int k = 0; k < TOPK; ++k) {
            e[12+k] = wcoef[n*TOPK+k];
            e[20+k] = 0.78539816339744830962f * (float)widx[n*TOPK+k]; // 2*pi*128/1024
        }
        sbb[rank] = make_float4(pxs, pys, rx, ry);
    }
    __syncthreads();

    // ------------------------------------------------------------------
    // Phase 2: render <=3 tiles with the LDS-resident sorted table
    // ------------------------------------------------------------------
    const int lane = n & 63;
    const int wv   = n >> 6;
    const float4 bb = sbb[wv * SEGSZ + lane];  // tile-independent: hoisted once
    const float* seg = lds + (wv * SEGSZ) * PSTRIDE;
    const float bg0 = bg[0], bg1 = bg[1], bg2 = bg[2];

    for (int t = blockIdx.x; t < NTILES; t += GRID) {
        const int tx = t % TILES_X, ty = t / TILES_X;
        const int x  = tx*8 + (lane & 7);
        const int y  = ty*8 + (lane >> 3);
        const float gx = (float)x + 0.5f, gy = (float)y + 0.5f;

        // per-lane box test of one primitive vs this 8x8 tile
        const float tcx = (float)(tx*8) + 4.0f, tcy = (float)(ty*8) + 4.0f;
        bool active = (fabsf(bb.x - tcx) <= bb.z + 3.5f) &&
                      (fabsf(bb.y - tcy) <= bb.w + 3.5f);
        unsigned long long mask = __ballot(active);

        float T = 1.f, cr = 0.f, cg = 0.f, cb = 0.f;
        while (mask) {
            int j = __ffsll((unsigned long long)mask) - 1;
            mask &= mask - 1;
            const float* h = seg + j * PSTRIDE;
            float4 q0 = *(const float4*)(h);       // broadcast reads, conflict-free
            float4 q1 = *(const float4*)(h + 4);
            float dx = q0.x - gx, dy = q0.y - gy;
            float pw = -0.5f*(q0.z*dx*dx + q1.x*dy*dy) - q0.w*dx*dy;
            if (__any(pw > -15.0f)) {
                float4 q2 = *(const float4*)(h + 8);
                float4 c0 = *(const float4*)(h + 12), c1 = *(const float4*)(h + 16);
                float4 w0 = *(const float4*)(h + 20), w1 = *(const float4*)(h + 24);
                float G = __expf(fminf(pw, 0.f));
                float tt = dx*q1.y + dy*q1.z;
                float wave = c0.x*__cosf(w0.x*tt) + c0.y*__cosf(w0.y*tt)
                           + c0.z*__cosf(w0.z*tt) + c0.w*__cosf(w0.w*tt)
                           + c1.x*__cosf(w1.x*tt) + c1.y*__cosf(w1.y*tt)
                           + c1.z*__cosf(w1.z*tt) + c1.w*__cosf(w1.w*tt);
                float a = fminf(fmaxf(q1.w * G * wave, 0.f), 0.99f);
                float wgt = a * T;
                cr += q2.x*wgt; cg += q2.y*wgt; cb += q2.z*wgt;
                T *= (1.f - a);
            }
        }
        part[wv*TILE + lane] = make_float4(cr, cg, cb, T);

        __syncthreads();

        // combine 8 depth segments front-to-back (wave 0)
        if (n < TILE) {
            float Ta = 1.f, fr = 0.f, fg = 0.f, fb = 0.f;
#pragma unroll
            for (int s = 0; s < NSEG; ++s) {
                float4 v = part[s*TILE + lane];
                fr += Ta * v.x; fg += Ta * v.y; fb += Ta * v.z;
                Ta *= v.w;
            }
            const int p = y*IMG + x;
            out[p]          = fr + bg0*Ta;
            out[NPIX + p]   = fg + bg1*Ta;
            out[2*NPIX + p] = fb + bg2*Ta;
        }
        __syncthreads();   // protect part[] before next tile overwrites
    }
}

extern "C" void kernel_launch(void* const* d_in, const int* in_sizes, int n_in,
                              void* d_out, int out_size, void* d_ws, size_t ws_size,
                              hipStream_t stream) {
    const float* colors  = (const float*)d_in[0];
    const float* opac    = (const float*)d_in[1];
    const float* bg      = (const float*)d_in[2];
    const float* pos     = (const float*)d_in[3];
    const float* scales  = (const float*)d_in[4];
    const float* rot     = (const float*)d_in[5];
    const float* wcoef   = (const float*)d_in[6];
    const int*   widx    = (const int*)d_in[7];
    // d_in[8] = cam_position (unused by forward)
    const float* view    = (const float*)d_in[9];
    const float* VP      = (const float*)d_in[10];

    hipLaunchKernelGGL(fused_kernel, dim3(GRID), dim3(NPRIM), 0, stream,
                       colors, opac, pos, scales, rot, wcoef, widx, view, VP,
                       bg, (float*)d_out);
}

// Round 2
// 90.057 us; speedup vs baseline: 1.0968x; 1.0968x over previous
//
#include <hip/hip_runtime.h>
#include <math.h>

// Problem constants (fixed by setup_inputs)
#define NPRIM   512
#define TOPK    8
#define PSTRIDE 28               // floats per primitive record (7 x float4)
#define IMG     200
#define NPIX    (IMG * IMG)
#define NSEG    8                // depth segments = waves per block
#define SEGSZ   (NPRIM / NSEG)   // 64 prims per wave
#define TILE    64               // 8x8 pixel tile, one pixel per lane
#define TILES_X (IMG / 8)        // 25
#define NTILES  (TILES_X * TILES_X)  // 625
#define GRID    209              // ceil(625/3): <=3 tiles/block, 1 block/CU

// LDS record layout (float4 granularity):
// f4[0]: px py conA conB | f4[1]: conC a2x a2y op | f4[2]: r g b pad
// f4[3..4]: coeff[8]     | f4[5..6]: omega[8]

__global__ __launch_bounds__(NPRIM) void fused_kernel(
    const float* __restrict__ colors,
    const float* __restrict__ opacities,
    const float* __restrict__ positions,
    const float* __restrict__ scales,
    const float* __restrict__ rotations,
    const float* __restrict__ wcoef,
    const int*   __restrict__ widx,
    const float* __restrict__ view,
    const float* __restrict__ VP,
    const float* __restrict__ bg,
    float* __restrict__ out)
{
    __shared__ float  lds[NPRIM * PSTRIDE];          // 57344 B, depth-sorted records
    __shared__ float4 sbb[NPRIM];                    //  8192 B, depth-sorted (px,py,rx,ry)
    __shared__ float4 part[NSEG * TILE];             //  8192 B
    __shared__ unsigned long long sk[NPRIM];         //  4096 B (sort keys / inv perm)

    const int n = threadIdx.x;

    // ------------------------------------------------------------------
    // Phase 1: per-primitive projection + bitonic depth sort, into LDS
    // ------------------------------------------------------------------
    {
        const float tanx = 0.57735026918962576451f; // tan(30 deg)
        const float fx = IMG / (2.0f * tanx);
        const float fy = IMG / (2.0f * tanx);

        float qr = rotations[n*4+0], qx = rotations[n*4+1];
        float qy = rotations[n*4+2], qz = rotations[n*4+3];
        float qn = sqrtf(qr*qr + qx*qx + qy*qy + qz*qz) + 1e-8f;
        qr /= qn; qx /= qn; qy /= qn; qz /= qn;
        float R00 = 1.f - 2.f*(qy*qy + qz*qz), R01 = 2.f*(qx*qy - qr*qz), R02 = 2.f*(qx*qz + qr*qy);
        float R10 = 2.f*(qx*qy + qr*qz), R11 = 1.f - 2.f*(qx*qx + qz*qz), R12 = 2.f*(qy*qz - qr*qx);
        float R20 = 2.f*(qx*qz - qr*qy), R21 = 2.f*(qy*qz + qr*qx), R22 = 1.f - 2.f*(qx*qx + qy*qy);

        float s0 = expf(scales[n*3+0]); s0 *= s0;
        float s1 = expf(scales[n*3+1]); s1 *= s1;
        float s2 = expf(scales[n*3+2]); s2 *= s2;

        float S00 = R00*R00*s0 + R01*R01*s1 + R02*R02*s2;
        float S01 = R00*R10*s0 + R01*R11*s1 + R02*R12*s2;
        float S02 = R00*R20*s0 + R01*R21*s1 + R02*R22*s2;
        float S11 = R10*R10*s0 + R11*R11*s1 + R12*R12*s2;
        float S12 = R10*R20*s0 + R11*R21*s1 + R12*R22*s2;
        float S22 = R20*R20*s0 + R21*R21*s1 + R22*R22*s2;

        float px_ = positions[n*3+0], py_ = positions[n*3+1], pz_ = positions[n*3+2];
        float t0 = view[0]*px_ + view[1]*py_ + view[2]*pz_  + view[3];
        float t1 = view[4]*px_ + view[5]*py_ + view[6]*pz_  + view[7];
        float t2 = view[8]*px_ + view[9]*py_ + view[10]*pz_ + view[11];
        float c0 = VP[0]*px_  + VP[1]*py_  + VP[2]*pz_  + VP[3];
        float c1 = VP[4]*px_  + VP[5]*py_  + VP[6]*pz_  + VP[7];
        float w  = VP[12]*px_ + VP[13]*py_ + VP[14]*pz_ + VP[15];

        float denom = (fabsf(w) > 1e-6f) ? w : 1e-6f;
        float pxs = (c0/denom * 0.5f + 0.5f) * (float)IMG;
        float pys = (c1/denom * 0.5f + 0.5f) * (float)IMG;

        float depth = t2;
        float tz = fmaxf(depth, 0.1f);
        float invz = 1.f / tz;
        float J00 = fx*invz, J02 = -fx*t0*invz*invz;
        float J11 = fy*invz, J12 = -fy*t1*invz*invz;

        float M00 = J00*view[0] + J02*view[8];
        float M01 = J00*view[1] + J02*view[9];
        float M02 = J00*view[2] + J02*view[10];
        float M10 = J11*view[4] + J12*view[8];
        float M11 = J11*view[5] + J12*view[9];
        float M12 = J11*view[6] + J12*view[10];

        float T00 = M00*S00 + M01*S01 + M02*S02;
        float T01 = M00*S01 + M01*S11 + M02*S12;
        float T02 = M00*S02 + M01*S12 + M02*S22;
        float T10 = M10*S00 + M11*S01 + M12*S02;
        float T11 = M10*S01 + M11*S11 + M12*S12;
        float T12 = M10*S02 + M11*S12 + M12*S22;
        float cA = T00*M00 + T01*M01 + T02*M02 + 0.3f;
        float cB = T00*M10 + T01*M11 + T02*M12;
        float cC = T10*M10 + T11*M11 + T12*M12 + 0.3f;
        float det  = fmaxf(cA*cC - cB*cB, 1e-12f);
        float idet = 1.f / det;
        float conA = cC*idet, conB = -cB*idet, conC = cA*idet;

        float a2x = M00*R00 + M01*R10 + M02*R20;
        float a2y = M10*R00 + M11*R10 + M12*R20;
        float an = sqrtf(a2x*a2x + a2y*a2y) + 1e-8f;
        a2x = (a2x/an) * (1.0f/(float)IMG);
        a2y = (a2y/an) * (1.0f/(float)IMG);

        bool valid = (depth > 0.1f) && (w > 1e-4f);
        float op = valid ? opacities[n] : 0.0f;

        // bbox of the {pw >= -15} ellipse: half-extents sqrt(2*15*cov_dilated_diag)
        float rx = valid ? sqrtf(fmaxf(30.f * cA, 0.f)) : -1e30f;
        float ry = valid ? sqrtf(fmaxf(30.f * cC, 0.f)) : -1e30f;

        // ---- stable argsort via hybrid bitonic sort ----------------------
        // key = (monotonic(depth_bits) << 32) | index  -> lexicographic
        // (depth asc, index asc) == jnp.argsort stable order.
        unsigned db = __float_as_uint(depth);
        db = (db & 0x80000000u) ? ~db : (db | 0x80000000u);
        unsigned long long kreg = ((unsigned long long)db << 32) | (unsigned)n;

        // thread n owns sort position n. partner distance < 64 -> shfl_xor
        // (no barrier, no LDS); distance >= 64 -> LDS exchange (6 stages).
#pragma unroll
        for (int k = 2; k <= NPRIM; k <<= 1) {
#pragma unroll
            for (int j = k >> 1; j > 0; j >>= 1) {
                unsigned long long vp;
                if (j >= 64) {
                    sk[n] = kreg;
                    __syncthreads();
                    vp = sk[n ^ j];
                    __syncthreads();
                } else {
                    vp = __shfl_xor(kreg, j, 64);
                }
                bool takeMin = (((n & k) == 0) == ((n & j) == 0));
                unsigned long long mn = (kreg < vp) ? kreg : vp;
                unsigned long long mx = (kreg < vp) ? vp : kreg;
                kreg = takeMin ? mn : mx;
            }
        }
        // invert permutation: thread at position n holds element (u32)kreg
        __syncthreads();
        int* sinv = (int*)sk;
        sinv[(unsigned)kreg] = n;       // sorted position of original index
        __syncthreads();
        int rank = sinv[n];

        float* e = lds + rank * PSTRIDE;
        e[0]=pxs; e[1]=pys; e[2]=conA; e[3]=conB; e[4]=conC;
        e[5]=a2x; e[6]=a2y; e[7]=op;
        e[8]=colors[n*3+0]; e[9]=colors[n*3+1]; e[10]=colors[n*3+2]; e[11]=0.f;
#pragma unroll
        for (int k = 0; k < TOPK; ++k) {
            e[12+k] = wcoef[n*TOPK+k];
            e[20+k] = 0.78539816339744830962f * (float)widx[n*TOPK+k]; // 2*pi*128/1024
        }
        sbb[rank] = make_float4(pxs, pys, rx, ry);
    }
    __syncthreads();

    // ------------------------------------------------------------------
    // Phase 2: render <=3 tiles with the LDS-resident sorted table
    // ------------------------------------------------------------------
    const int lane = n & 63;
    const int wv   = n >> 6;
    const float4 bb = sbb[wv * SEGSZ + lane];  // tile-independent: hoisted once
    const float* seg = lds + (wv * SEGSZ) * PSTRIDE;
    const float bg0 = bg[0], bg1 = bg[1], bg2 = bg[2];

    for (int t = blockIdx.x; t < NTILES; t += GRID) {
        const int tx = t % TILES_X, ty = t / TILES_X;
        const int x  = tx*8 + (lane & 7);
        const int y  = ty*8 + (lane >> 3);
        const float gx = (float)x + 0.5f, gy = (float)y + 0.5f;

        // per-lane box test of one primitive vs this 8x8 tile
        const float tcx = (float)(tx*8) + 4.0f, tcy = (float)(ty*8) + 4.0f;
        bool active = (fabsf(bb.x - tcx) <= bb.z + 3.5f) &&
                      (fabsf(bb.y - tcy) <= bb.w + 3.5f);
        unsigned long long mask = __ballot(active);

        float T = 1.f, cr = 0.f, cg = 0.f, cb = 0.f;
        while (mask) {
            int j = __ffsll((unsigned long long)mask) - 1;
            mask &= mask - 1;
            const float* h = seg + j * PSTRIDE;
            float4 q0 = *(const float4*)(h);       // broadcast reads, conflict-free
            float4 q1 = *(const float4*)(h + 4);
            float dx = q0.x - gx, dy = q0.y - gy;
            float pw = -0.5f*(q0.z*dx*dx + q1.x*dy*dy) - q0.w*dx*dy;
            if (__any(pw > -15.0f)) {
                float4 q2 = *(const float4*)(h + 8);
                float4 c0 = *(const float4*)(h + 12), c1 = *(const float4*)(h + 16);
                float4 w0 = *(const float4*)(h + 20), w1 = *(const float4*)(h + 24);
                float G = __expf(fminf(pw, 0.f));
                float tt = dx*q1.y + dy*q1.z;
                float wave = c0.x*__cosf(w0.x*tt) + c0.y*__cosf(w0.y*tt)
                           + c0.z*__cosf(w0.z*tt) + c0.w*__cosf(w0.w*tt)
                           + c1.x*__cosf(w1.x*tt) + c1.y*__cosf(w1.y*tt)
                           + c1.z*__cosf(w1.z*tt) + c1.w*__cosf(w1.w*tt);
                float a = fminf(fmaxf(q1.w * G * wave, 0.f), 0.99f);
                float wgt = a * T;
                cr += q2.x*wgt; cg += q2.y*wgt; cb += q2.z*wgt;
                T *= (1.f - a);
            }
        }
        part[wv*TILE + lane] = make_float4(cr, cg, cb, T);

        __syncthreads();

        // combine 8 depth segments front-to-back (wave 0)
        if (n < TILE) {
            float Ta = 1.f, fr = 0.f, fg = 0.f, fb = 0.f;
#pragma unroll
            for (int s = 0; s < NSEG; ++s) {
                float4 v = part[s*TILE + lane];
                fr += Ta * v.x; fg += Ta * v.y; fb += Ta * v.z;
                Ta *= v.w;
            }
            const int p = y*IMG + x;
            out[p]          = fr + bg0*Ta;
            out[NPIX + p]   = fg + bg1*Ta;
            out[2*NPIX + p] = fb + bg2*Ta;
        }
        __syncthreads();   // protect part[] before next tile overwrites
    }
}

extern "C" void kernel_launch(void* const* d_in, const int* in_sizes, int n_in,
                              void* d_out, int out_size, void* d_ws, size_t ws_size,
                              hipStream_t stream) {
    const float* colors  = (const float*)d_in[0];
    const float* opac    = (const float*)d_in[1];
    const float* bg      = (const float*)d_in[2];
    const float* pos     = (const float*)d_in[3];
    const float* scales  = (const float*)d_in[4];
    const float* rot     = (const float*)d_in[5];
    const float* wcoef   = (const float*)d_in[6];
    const int*   widx    = (const int*)d_in[7];
    // d_in[8] = cam_position (unused by forward)
    const float* view    = (const float*)d_in[9];
    const float* VP      = (const float*)d_in[10];
    (void)d_ws; (void)ws_size;

    hipLaunchKernelGGL(fused_kernel, dim3(GRID), dim3(NPRIM), 0, stream,
                       colors, opac, pos, scales, rot, wcoef, widx, view, VP,
                       bg, (float*)d_out);
}

// Round 3
// 88.886 us; speedup vs baseline: 1.1113x; 1.0132x over previous
//
#include <hip/hip_runtime.h>
#include <math.h>

// Problem constants (fixed by setup_inputs)
#define NPRIM   512
#define TOPK    8
#define PSTRIDE 28               // floats per primitive record (7 x float4, 112 B -> 16B aligned)
#define IMG     200
#define NPIX    (IMG * IMG)
#define NSEG    8                // depth segments = waves per block
#define SEGSZ   (NPRIM / NSEG)   // 64 prims per wave
#define TILE    64               // 8x8 pixel tile, one pixel per lane
#define TILES_X (IMG / 8)        // 25
#define NTILES  (TILES_X * TILES_X)  // 625
#define GRID    209              // ceil(625/3): <=3 tiles/block, 1 block/CU

// LDS record layout (float4 granularity):
// f4[0]: px py conA conB | f4[1]: conC a2x a2y op | f4[2]: r g b pad
// f4[3..4]: coeff[8]     | f4[5..6]: omega[8]

__global__ __launch_bounds__(NPRIM) void fused_kernel(
    const float* __restrict__ colors,
    const float* __restrict__ opacities,
    const float* __restrict__ positions,
    const float* __restrict__ scales,
    const float* __restrict__ rotations,
    const float* __restrict__ wcoef,
    const int*   __restrict__ widx,
    const float* __restrict__ view,
    const float* __restrict__ VP,
    const float* __restrict__ bg,
    float* __restrict__ out)
{
    __shared__ float  lds[NPRIM * PSTRIDE];   // 57344 B, depth-sorted records
    __shared__ float4 sbb[NPRIM];             //  8192 B, depth-sorted (px,py,rx,ry)
    // sort keys (phase 1) and per-segment partials (phase 2) have disjoint
    // lifetimes -> union them (8192 B). Total LDS = 73728 B.
    __shared__ union {
        unsigned long long sk[2][NPRIM];      // double-buffered sort keys
        float4 part[NSEG * TILE];
    } u;

    const int n = threadIdx.x;

    // ------------------------------------------------------------------
    // Phase 1: per-primitive projection + bitonic depth sort, into LDS
    // ------------------------------------------------------------------
    {
        // ---- vectorized global loads (hipcc won't auto-vectorize these)
        float4 q   = ((const float4*)rotations)[n];              // 16B aligned
        float4 cfa = ((const float4*)wcoef)[2*n];                // 32B-aligned pairs
        float4 cfb = ((const float4*)wcoef)[2*n+1];
        int4   ia  = ((const int4*)widx)[2*n];
        int4   ib  = ((const int4*)widx)[2*n+1];
        float sc0 = scales[n*3+0], sc1 = scales[n*3+1], sc2 = scales[n*3+2];
        float px_ = positions[n*3+0], py_ = positions[n*3+1], pz_ = positions[n*3+2];
        float col0 = colors[n*3+0], col1 = colors[n*3+1], col2 = colors[n*3+2];
        float opa = opacities[n];

        const float tanx = 0.57735026918962576451f; // tan(30 deg)
        const float fx = IMG / (2.0f * tanx);
        const float fy = IMG / (2.0f * tanx);

        float qr = q.x, qx = q.y, qy = q.z, qz = q.w;
        float qn = sqrtf(qr*qr + qx*qx + qy*qy + qz*qz) + 1e-8f;
        qr /= qn; qx /= qn; qy /= qn; qz /= qn;
        float R00 = 1.f - 2.f*(qy*qy + qz*qz), R01 = 2.f*(qx*qy - qr*qz), R02 = 2.f*(qx*qz + qr*qy);
        float R10 = 2.f*(qx*qy + qr*qz), R11 = 1.f - 2.f*(qx*qx + qz*qz), R12 = 2.f*(qy*qz - qr*qx);
        float R20 = 2.f*(qx*qz - qr*qy), R21 = 2.f*(qy*qz + qr*qx), R22 = 1.f - 2.f*(qx*qx + qy*qy);

        float s0 = expf(sc0); s0 *= s0;
        float s1 = expf(sc1); s1 *= s1;
        float s2 = expf(sc2); s2 *= s2;

        float S00 = R00*R00*s0 + R01*R01*s1 + R02*R02*s2;
        float S01 = R00*R10*s0 + R01*R11*s1 + R02*R12*s2;
        float S02 = R00*R20*s0 + R01*R21*s1 + R02*R22*s2;
        float S11 = R10*R10*s0 + R11*R11*s1 + R12*R12*s2;
        float S12 = R10*R20*s0 + R11*R21*s1 + R12*R22*s2;
        float S22 = R20*R20*s0 + R21*R21*s1 + R22*R22*s2;

        float t0 = view[0]*px_ + view[1]*py_ + view[2]*pz_  + view[3];
        float t1 = view[4]*px_ + view[5]*py_ + view[6]*pz_  + view[7];
        float t2 = view[8]*px_ + view[9]*py_ + view[10]*pz_ + view[11];
        float c0 = VP[0]*px_  + VP[1]*py_  + VP[2]*pz_  + VP[3];
        float c1 = VP[4]*px_  + VP[5]*py_  + VP[6]*pz_  + VP[7];
        float w  = VP[12]*px_ + VP[13]*py_ + VP[14]*pz_ + VP[15];

        float denom = (fabsf(w) > 1e-6f) ? w : 1e-6f;
        float pxs = (c0/denom * 0.5f + 0.5f) * (float)IMG;
        float pys = (c1/denom * 0.5f + 0.5f) * (float)IMG;

        float depth = t2;
        float tz = fmaxf(depth, 0.1f);
        float invz = 1.f / tz;
        float J00 = fx*invz, J02 = -fx*t0*invz*invz;
        float J11 = fy*invz, J12 = -fy*t1*invz*invz;

        float M00 = J00*view[0] + J02*view[8];
        float M01 = J00*view[1] + J02*view[9];
        float M02 = J00*view[2] + J02*view[10];
        float M10 = J11*view[4] + J12*view[8];
        float M11 = J11*view[5] + J12*view[9];
        float M12 = J11*view[6] + J12*view[10];

        float T00 = M00*S00 + M01*S01 + M02*S02;
        float T01 = M00*S01 + M01*S11 + M02*S12;
        float T02 = M00*S02 + M01*S12 + M02*S22;
        float T10 = M10*S00 + M11*S01 + M12*S02;
        float T11 = M10*S01 + M11*S11 + M12*S12;
        float T12 = M10*S02 + M11*S12 + M12*S22;
        float cA = T00*M00 + T01*M01 + T02*M02 + 0.3f;
        float cB = T00*M10 + T01*M11 + T02*M12;
        float cC = T10*M10 + T11*M11 + T12*M12 + 0.3f;
        float det  = fmaxf(cA*cC - cB*cB, 1e-12f);
        float idet = 1.f / det;
        float conA = cC*idet, conB = -cB*idet, conC = cA*idet;

        float a2x = M00*R00 + M01*R10 + M02*R20;
        float a2y = M10*R00 + M11*R10 + M12*R20;
        float an = sqrtf(a2x*a2x + a2y*a2y) + 1e-8f;
        a2x = (a2x/an) * (1.0f/(float)IMG);
        a2y = (a2y/an) * (1.0f/(float)IMG);

        bool valid = (depth > 0.1f) && (w > 1e-4f);
        float op = valid ? opa : 0.0f;

        // bbox of the {pw >= -15} ellipse: half-extents sqrt(2*15*cov_dilated_diag)
        float rx = valid ? sqrtf(fmaxf(30.f * cA, 0.f)) : -1e30f;
        float ry = valid ? sqrtf(fmaxf(30.f * cC, 0.f)) : -1e30f;

        // ---- stable argsort via hybrid bitonic sort ----------------------
        // key = (monotonic(depth_bits) << 32) | index  -> lexicographic
        // (depth asc, index asc) == jnp.argsort stable order.
        unsigned db = __float_as_uint(depth);
        db = (db & 0x80000000u) ? ~db : (db | 0x80000000u);
        unsigned long long kreg = ((unsigned long long)db << 32) | (unsigned)n;

        // thread n owns sort position n. partner distance < 64 -> shfl_xor
        // (no barrier); distance >= 64 -> LDS exchange, DOUBLE-BUFFERED so
        // each of the 6 cross-wave stages needs only ONE barrier (the next
        // stage writes the other buffer; barrier collectivity prevents any
        // wave from lapping a buffer before all reads of it completed).
        int ls = 0;
#pragma unroll
        for (int k = 2; k <= NPRIM; k <<= 1) {
#pragma unroll
            for (int j = k >> 1; j > 0; j >>= 1) {
                unsigned long long vp;
                if (j >= 64) {
                    u.sk[ls][n] = kreg;
                    __syncthreads();
                    vp = u.sk[ls][n ^ j];
                    ls ^= 1;
                } else {
                    vp = __shfl_xor(kreg, j, 64);
                }
                bool takeMin = (((n & k) == 0) == ((n & j) == 0));
                unsigned long long mn = (kreg < vp) ? kreg : vp;
                unsigned long long mx = (kreg < vp) ? vp : kreg;
                kreg = takeMin ? mn : mx;
            }
        }
        // invert permutation: thread at sorted position n holds original
        // index (u32)kreg. Write into buffer 0 (6 stages toggled ls back to
        // 0; buf0's last reads were stage 4, fenced by stage 5's barrier).
        int* sinv = (int*)u.sk[0];
        sinv[(unsigned)kreg] = n;       // sorted position of original index
        __syncthreads();
        int rank = sinv[n];

        const float om = 0.78539816339744830962f; // 2*pi*128/1024
        float4* e4 = (float4*)(lds + rank * PSTRIDE);
        e4[0] = make_float4(pxs, pys, conA, conB);
        e4[1] = make_float4(conC, a2x, a2y, op);
        e4[2] = make_float4(col0, col1, col2, 0.f);
        e4[3] = cfa;
        e4[4] = cfb;
        e4[5] = make_float4(om*(float)ia.x, om*(float)ia.y, om*(float)ia.z, om*(float)ia.w);
        e4[6] = make_float4(om*(float)ib.x, om*(float)ib.y, om*(float)ib.z, om*(float)ib.w);
        sbb[rank] = make_float4(pxs, pys, rx, ry);
    }
    __syncthreads();

    // ------------------------------------------------------------------
    // Phase 2: render <=3 tiles with the LDS-resident sorted table
    // ------------------------------------------------------------------
    const int lane = n & 63;
    const int wv   = n >> 6;
    const float4 bb = sbb[wv * SEGSZ + lane];  // tile-independent: hoisted once
    const float* seg = lds + (wv * SEGSZ) * PSTRIDE;
    const float bg0 = bg[0], bg1 = bg[1], bg2 = bg[2];

    for (int t = blockIdx.x; t < NTILES; t += GRID) {
        const int tx = t % TILES_X, ty = t / TILES_X;
        const int x  = tx*8 + (lane & 7);
        const int y  = ty*8 + (lane >> 3);
        const float gx = (float)x + 0.5f, gy = (float)y + 0.5f;

        // per-lane box test of one primitive vs this 8x8 tile
        const float tcx = (float)(tx*8) + 4.0f, tcy = (float)(ty*8) + 4.0f;
        bool active = (fabsf(bb.x - tcx) <= bb.z + 3.5f) &&
                      (fabsf(bb.y - tcy) <= bb.w + 3.5f);
        unsigned long long mask = __ballot(active);

        float T = 1.f, cr = 0.f, cg = 0.f, cb = 0.f;
        while (mask) {
            int j = __ffsll((unsigned long long)mask) - 1;
            mask &= mask - 1;
            const float* h = seg + j * PSTRIDE;
            float4 q0 = *(const float4*)(h);       // broadcast reads, conflict-free
            float4 q1 = *(const float4*)(h + 4);
            float dx = q0.x - gx, dy = q0.y - gy;
            float pw = -0.5f*(q0.z*dx*dx + q1.x*dy*dy) - q0.w*dx*dy;
            if (__any(pw > -15.0f)) {
                float4 q2 = *(const float4*)(h + 8);
                float4 c0 = *(const float4*)(h + 12), c1 = *(const float4*)(h + 16);
                float4 w0 = *(const float4*)(h + 20), w1 = *(const float4*)(h + 24);
                float G = __expf(fminf(pw, 0.f));
                float tt = dx*q1.y + dy*q1.z;
                float wave = c0.x*__cosf(w0.x*tt) + c0.y*__cosf(w0.y*tt)
                           + c0.z*__cosf(w0.z*tt) + c0.w*__cosf(w0.w*tt)
                           + c1.x*__cosf(w1.x*tt) + c1.y*__cosf(w1.y*tt)
                           + c1.z*__cosf(w1.z*tt) + c1.w*__cosf(w1.w*tt);
                float a = fminf(fmaxf(q1.w * G * wave, 0.f), 0.99f);
                float wgt = a * T;
                cr += q2.x*wgt; cg += q2.y*wgt; cb += q2.z*wgt;
                T *= (1.f - a);
            }
        }
        u.part[wv*TILE + lane] = make_float4(cr, cg, cb, T);

        __syncthreads();

        // combine 8 depth segments front-to-back (wave 0)
        if (n < TILE) {
            float Ta = 1.f, fr = 0.f, fg = 0.f, fb = 0.f;
#pragma unroll
            for (int s = 0; s < NSEG; ++s) {
                float4 v = u.part[s*TILE + lane];
                fr += Ta * v.x; fg += Ta * v.y; fb += Ta * v.z;
                Ta *= v.w;
            }
            const int p = y*IMG + x;
            out[p]          = fr + bg0*Ta;
            out[NPIX + p]   = fg + bg1*Ta;
            out[2*NPIX + p] = fb + bg2*Ta;
        }
        __syncthreads();   // protect part[] before next tile overwrites
    }
}

extern "C" void kernel_launch(void* const* d_in, const int* in_sizes, int n_in,
                              void* d_out, int out_size, void* d_ws, size_t ws_size,
                              hipStream_t stream) {
    const float* colors  = (const float*)d_in[0];
    const float* opac    = (const float*)d_in[1];
    const float* bg      = (const float*)d_in[2];
    const float* pos     = (const float*)d_in[3];
    const float* scales  = (const float*)d_in[4];
    const float* rot     = (const float*)d_in[5];
    const float* wcoef   = (const float*)d_in[6];
    const int*   widx    = (const int*)d_in[7];
    // d_in[8] = cam_position (unused by forward)
    const float* view    = (const float*)d_in[9];
    const float* VP      = (const float*)d_in[10];
    (void)d_ws; (void)ws_size;

    hipLaunchKernelGGL(fused_kernel, dim3(GRID), dim3(NPRIM), 0, stream,
                       colors, opac, pos, scales, rot, wcoef, widx, view, VP,
                       bg, (float*)d_out);
}

// Round 4
// 88.365 us; speedup vs baseline: 1.1178x; 1.0059x over previous
//
#include <hip/hip_runtime.h>
#include <math.h>

// Problem constants (fixed by setup_inputs)
#define NPRIM   512
#define TOPK    8
#define PSTRIDE 28               // floats per primitive record (7 x float4, 112 B)
#define IMG     200
#define NPIX    (IMG * IMG)
#define NSEG    8                // depth segments = waves per block
#define SEGSZ   (NPRIM / NSEG)   // 64 prims per wave
#define TILES_X (IMG / 8)        // 25
#define NTILES  (TILES_X * TILES_X)  // 625
#define GRID    209              // ceil(625/3): <=3 tiles/block, 1 block/CU
#define TPB     3                // max tiles per block

// LDS record layout (float4 granularity), stored at ORIGINAL index n:
// f4[0]: px py conA conB | f4[1]: conC a2x a2y op | f4[2]: r g b pad
// f4[3..4]: coeff[8]     | f4[5..6]: omega[8]
// perm[rank] = original index  (depth-stable order); phase 2 reads via perm.

__global__ __launch_bounds__(NPRIM) void fused_kernel(
    const float* __restrict__ colors,
    const float* __restrict__ opacities,
    const float* __restrict__ positions,
    const float* __restrict__ scales,
    const float* __restrict__ rotations,
    const float* __restrict__ wcoef,
    const int*   __restrict__ widx,
    const float* __restrict__ view,
    const float* __restrict__ VP,
    const float* __restrict__ bg,
    float* __restrict__ out)
{
    __shared__ float  lds[NPRIM * PSTRIDE];   // 57344 B, records in ORIGINAL order
    __shared__ float4 sbb[NPRIM];             //  8192 B, (px,py,rx,ry) original order
    __shared__ int    perm[NPRIM];            //  2048 B, rank -> original index
    // sort keys (phase 1) and per-tile partials (phase 2): disjoint lifetimes.
    __shared__ union {
        unsigned long long sk[2][NPRIM];      //  8192 B double-buffered sort keys
        float4 part[TPB][NSEG][SEGSZ];        // 24576 B per-tile segment partials
    } u;                                      // total LDS = 92160 B (1 blk/CU)

    const int n = threadIdx.x;

    // ------------------------------------------------------------------
    // Phase 1: projection into LDS (original order) + bitonic depth sort
    // ------------------------------------------------------------------
    {
        // ---- vectorized global loads (hipcc won't auto-vectorize these)
        float4 q   = ((const float4*)rotations)[n];              // 16B aligned
        float4 cfa = ((const float4*)wcoef)[2*n];                // 32B record
        float4 cfb = ((const float4*)wcoef)[2*n+1];
        int4   ia  = ((const int4*)widx)[2*n];
        int4   ib  = ((const int4*)widx)[2*n+1];
        float sc0 = scales[n*3+0], sc1 = scales[n*3+1], sc2 = scales[n*3+2];
        float px_ = positions[n*3+0], py_ = positions[n*3+1], pz_ = positions[n*3+2];
        float col0 = colors[n*3+0], col1 = colors[n*3+1], col2 = colors[n*3+2];
        float opa = opacities[n];

        const float tanx = 0.57735026918962576451f; // tan(30 deg)
        const float fx = IMG / (2.0f * tanx);
        const float fy = IMG / (2.0f * tanx);

        float qr = q.x, qx = q.y, qy = q.z, qz = q.w;
        float qn = sqrtf(qr*qr + qx*qx + qy*qy + qz*qz) + 1e-8f;
        qr /= qn; qx /= qn; qy /= qn; qz /= qn;
        float R00 = 1.f - 2.f*(qy*qy + qz*qz), R01 = 2.f*(qx*qy - qr*qz), R02 = 2.f*(qx*qz + qr*qy);
        float R10 = 2.f*(qx*qy + qr*qz), R11 = 1.f - 2.f*(qx*qx + qz*qz), R12 = 2.f*(qy*qz - qr*qx);
        float R20 = 2.f*(qx*qz - qr*qy), R21 = 2.f*(qy*qz + qr*qx), R22 = 1.f - 2.f*(qx*qx + qy*qy);

        float s0 = expf(sc0); s0 *= s0;
        float s1 = expf(sc1); s1 *= s1;
        float s2 = expf(sc2); s2 *= s2;

        float S00 = R00*R00*s0 + R01*R01*s1 + R02*R02*s2;
        float S01 = R00*R10*s0 + R01*R11*s1 + R02*R12*s2;
        float S02 = R00*R20*s0 + R01*R21*s1 + R02*R22*s2;
        float S11 = R10*R10*s0 + R11*R11*s1 + R12*R12*s2;
        float S12 = R10*R20*s0 + R11*R21*s1 + R12*R22*s2;
        float S22 = R20*R20*s0 + R21*R21*s1 + R22*R22*s2;

        float t0 = view[0]*px_ + view[1]*py_ + view[2]*pz_  + view[3];
        float t1 = view[4]*px_ + view[5]*py_ + view[6]*pz_  + view[7];
        float t2 = view[8]*px_ + view[9]*py_ + view[10]*pz_ + view[11];
        float c0 = VP[0]*px_  + VP[1]*py_  + VP[2]*pz_  + VP[3];
        float c1 = VP[4]*px_  + VP[5]*py_  + VP[6]*pz_  + VP[7];
        float w  = VP[12]*px_ + VP[13]*py_ + VP[14]*pz_ + VP[15];

        float denom = (fabsf(w) > 1e-6f) ? w : 1e-6f;
        float pxs = (c0/denom * 0.5f + 0.5f) * (float)IMG;
        float pys = (c1/denom * 0.5f + 0.5f) * (float)IMG;

        float depth = t2;
        float tz = fmaxf(depth, 0.1f);
        float invz = 1.f / tz;
        float J00 = fx*invz, J02 = -fx*t0*invz*invz;
        float J11 = fy*invz, J12 = -fy*t1*invz*invz;

        float M00 = J00*view[0] + J02*view[8];
        float M01 = J00*view[1] + J02*view[9];
        float M02 = J00*view[2] + J02*view[10];
        float M10 = J11*view[4] + J12*view[8];
        float M11 = J11*view[5] + J12*view[9];
        float M12 = J11*view[6] + J12*view[10];

        float T00 = M00*S00 + M01*S01 + M02*S02;
        float T01 = M00*S01 + M01*S11 + M02*S12;
        float T02 = M00*S02 + M01*S12 + M02*S22;
        float T10 = M10*S00 + M11*S01 + M12*S02;
        float T11 = M10*S01 + M11*S11 + M12*S12;
        float T12 = M10*S02 + M11*S12 + M12*S22;
        float cA = T00*M00 + T01*M01 + T02*M02 + 0.3f;
        float cB = T00*M10 + T01*M11 + T02*M12;
        float cC = T10*M10 + T11*M11 + T12*M12 + 0.3f;
        float det  = fmaxf(cA*cC - cB*cB, 1e-12f);
        float idet = 1.f / det;
        float conA = cC*idet, conB = -cB*idet, conC = cA*idet;

        float a2x = M00*R00 + M01*R10 + M02*R20;
        float a2y = M10*R00 + M11*R10 + M12*R20;
        float an = sqrtf(a2x*a2x + a2y*a2y) + 1e-8f;
        a2x = (a2x/an) * (1.0f/(float)IMG);
        a2y = (a2y/an) * (1.0f/(float)IMG);

        bool valid = (depth > 0.1f) && (w > 1e-4f);
        float op = valid ? opa : 0.0f;

        // bbox of the {pw >= -15} ellipse: half-extents sqrt(2*15*cov_dilated_diag)
        float rx = valid ? sqrtf(fmaxf(30.f * cA, 0.f)) : -1e30f;
        float ry = valid ? sqrtf(fmaxf(30.f * cC, 0.f)) : -1e30f;

        // ---- record write at ORIGINAL slot n: independent of the sort, so
        // the compiler is free to issue these ds_writes during sort stages.
        const float om = 0.78539816339744830962f; // 2*pi*128/1024
        float4* e4 = (float4*)(lds + n * PSTRIDE);
        e4[0] = make_float4(pxs, pys, conA, conB);
        e4[1] = make_float4(conC, a2x, a2y, op);
        e4[2] = make_float4(col0, col1, col2, 0.f);
        e4[3] = cfa;
        e4[4] = cfb;
        e4[5] = make_float4(om*(float)ia.x, om*(float)ia.y, om*(float)ia.z, om*(float)ia.w);
        e4[6] = make_float4(om*(float)ib.x, om*(float)ib.y, om*(float)ib.z, om*(float)ib.w);
        sbb[n] = make_float4(pxs, pys, rx, ry);

        // ---- stable argsort via hybrid bitonic sort ----------------------
        // key = (monotonic(depth_bits) << 32) | index  -> lexicographic
        // (depth asc, index asc) == jnp.argsort stable order.
        unsigned db = __float_as_uint(depth);
        db = (db & 0x80000000u) ? ~db : (db | 0x80000000u);
        unsigned long long kreg = ((unsigned long long)db << 32) | (unsigned)n;

        // thread n owns sort position n. partner distance < 64 -> shfl_xor
        // (no barrier); distance >= 64 -> LDS exchange, DOUBLE-BUFFERED so
        // each of the 6 cross-wave stages needs only ONE barrier.
        int ls = 0;
#pragma unroll
        for (int k = 2; k <= NPRIM; k <<= 1) {
#pragma unroll
            for (int j = k >> 1; j > 0; j >>= 1) {
                unsigned long long vp;
                if (j >= 64) {
                    u.sk[ls][n] = kreg;
                    __syncthreads();
                    vp = u.sk[ls][n ^ j];
                    ls ^= 1;
                } else {
                    vp = __shfl_xor(kreg, j, 64);
                }
                bool takeMin = (((n & k) == 0) == ((n & j) == 0));
                unsigned long long mn = (kreg < vp) ? kreg : vp;
                unsigned long long mx = (kreg < vp) ? vp : kreg;
                kreg = takeMin ? mn : mx;
            }
        }
        // thread at sorted position n holds original index (u32)kreg:
        // that IS the permutation -- no inversion pass needed.
        perm[n] = (int)(unsigned)kreg;
    }
    __syncthreads();   // records + sbb + perm all visible

    // ------------------------------------------------------------------
    // Phase 2: render <=3 tiles via perm indirection; NO inter-tile barriers
    // ------------------------------------------------------------------
    const int lane = n & 63;
    const int wv   = n >> 6;
    const int   pidx = perm[wv * SEGSZ + lane]; // original idx of this rank slot
    const float4 bb  = sbb[pidx];               // tile-independent: hoisted once
    const int*  segp = perm + wv * SEGSZ;
    const float bg0 = bg[0], bg1 = bg[1], bg2 = bg[2];

#pragma unroll
    for (int t3 = 0; t3 < TPB; ++t3) {
        const int t = blockIdx.x + t3 * GRID;   // uniform across block
        if (t >= NTILES) break;
        const int tx = t % TILES_X, ty = t / TILES_X;
        const int x  = tx*8 + (lane & 7);
        const int y  = ty*8 + (lane >> 3);
        const float gx = (float)x + 0.5f, gy = (float)y + 0.5f;

        // per-lane box test of one primitive vs this 8x8 tile
        const float tcx = (float)(tx*8) + 4.0f, tcy = (float)(ty*8) + 4.0f;
        bool active = (fabsf(bb.x - tcx) <= bb.z + 3.5f) &&
                      (fabsf(bb.y - tcy) <= bb.w + 3.5f);
        unsigned long long mask = __ballot(active);

        float T = 1.f, cr = 0.f, cg = 0.f, cb = 0.f;
        while (mask) {
            int j = __ffsll((unsigned long long)mask) - 1;
            mask &= mask - 1;
            const float* h = lds + segp[j] * PSTRIDE;  // broadcast perm + record
            float4 q0 = *(const float4*)(h);
            float4 q1 = *(const float4*)(h + 4);
            float dx = q0.x - gx, dy = q0.y - gy;
            float pw = -0.5f*(q0.z*dx*dx + q1.x*dy*dy) - q0.w*dx*dy;
            if (__any(pw > -15.0f)) {
                float4 q2 = *(const float4*)(h + 8);
                float4 c0 = *(const float4*)(h + 12), c1 = *(const float4*)(h + 16);
                float4 w0 = *(const float4*)(h + 20), w1 = *(const float4*)(h + 24);
                float G = __expf(fminf(pw, 0.f));
                float tt = dx*q1.y + dy*q1.z;
                float wave = c0.x*__cosf(w0.x*tt) + c0.y*__cosf(w0.y*tt)
                           + c0.z*__cosf(w0.z*tt) + c0.w*__cosf(w0.w*tt)
                           + c1.x*__cosf(w1.x*tt) + c1.y*__cosf(w1.y*tt)
                           + c1.z*__cosf(w1.z*tt) + c1.w*__cosf(w1.w*tt);
                float a = fminf(fmaxf(q1.w * G * wave, 0.f), 0.99f);
                float wgt = a * T;
                cr += q2.x*wgt; cg += q2.y*wgt; cb += q2.z*wgt;
                T *= (1.f - a);
            }
        }
        u.part[t3][wv][lane] = make_float4(cr, cg, cb, T);
    }

    __syncthreads();   // single barrier: all tiles' partials ready

    // combine: wave t3 (t3 < TPB) composes tile blockIdx + t3*GRID
    if (wv < TPB) {
        const int t = blockIdx.x + wv * GRID;
        if (t < NTILES) {
            const int tx = t % TILES_X, ty = t / TILES_X;
            const int x  = tx*8 + (lane & 7);
            const int y  = ty*8 + (lane >> 3);
            float Ta = 1.f, fr = 0.f, fg = 0.f, fb = 0.f;
#pragma unroll
            for (int s = 0; s < NSEG; ++s) {
                float4 v = u.part[wv][s][lane];
                fr += Ta * v.x; fg += Ta * v.y; fb += Ta * v.z;
                Ta *= v.w;
            }
            const int p = y*IMG + x;
            out[p]          = fr + bg0*Ta;
            out[NPIX + p]   = fg + bg1*Ta;
            out[2*NPIX + p] = fb + bg2*Ta;
        }
    }
}

extern "C" void kernel_launch(void* const* d_in, const int* in_sizes, int n_in,
                              void* d_out, int out_size, void* d_ws, size_t ws_size,
                              hipStream_t stream) {
    const float* colors  = (const float*)d_in[0];
    const float* opac    = (const float*)d_in[1];
    const float* bg      = (const float*)d_in[2];
    const float* pos     = (const float*)d_in[3];
    const float* scales  = (const float*)d_in[4];
    const float* rot     = (const float*)d_in[5];
    const float* wcoef   = (const float*)d_in[6];
    const int*   widx    = (const int*)d_in[7];
    // d_in[8] = cam_position (unused by forward)
    const float* view    = (const float*)d_in[9];
    const float* VP      = (const float*)d_in[10];
    (void)d_ws; (void)ws_size;

    hipLaunchKernelGGL(fused_kernel, dim3(GRID), dim3(NPRIM), 0, stream,
                       colors, opac, pos, scales, rot, wcoef, widx, view, VP,
                       bg, (float*)d_out);
}